// Round 14
// baseline (281.932 us; speedup 1.0000x reference)
//
#include <hip/hip_runtime.h>
#include <hip/hip_bf16.h>

#define SELU_L 1.0507009873554805f
#define SELU_A 1.6732632423543772f

typedef float  floatx4 __attribute__((ext_vector_type(4)));
typedef short  bf16x8  __attribute__((ext_vector_type(8)));

__device__ __forceinline__ float selu(float x) {
    return x > 0.f ? SELU_L * x : SELU_L * SELU_A * (expf(x) - 1.f);
}
__device__ __forceinline__ float fast_rcp(float x) {
    return __builtin_amdgcn_rcpf(x);
}
__device__ __forceinline__ unsigned short bf16_rne(float f) {
    unsigned int u = __float_as_uint(f);
    u += 0x7fffu + ((u >> 16) & 1u);
    return (unsigned short)(u >> 16);
}
__device__ __forceinline__ void cvt8(const float* __restrict__ p,
                                     bf16x8& h8, bf16x8& l8) {
    float4 v0 = *reinterpret_cast<const float4*>(p);
    float4 v1 = *reinterpret_cast<const float4*>(p + 4);
    float f[8] = {v0.x, v0.y, v0.z, v0.w, v1.x, v1.y, v1.z, v1.w};
#pragma unroll
    for (int j = 0; j < 8; ++j) {
        const unsigned short h = bf16_rne(f[j]);
        const float hf = __uint_as_float((unsigned)h << 16);
        const unsigned short l = bf16_rne(f[j] - hf);
        h8[j] = (short)h;
        l8[j] = (short)l;
    }
}

// ---------------- Kernel W: convert fc_w into bf16 hi/lo planes -------------
__global__ __launch_bounds__(256) void convert_w_pad(
    const float* __restrict__ w, ushort* __restrict__ whi, ushort* __restrict__ wlo,
    double* __restrict__ accs)
{
    const int row = blockIdx.x;           // 0..127
    const int t   = threadIdx.x;
    if (row == 0 && t < 64) {
        for (int i = t; i < 257; i += 64) accs[i] = 0.0;
    }
    if (t < 196) {
        float4 v = reinterpret_cast<const float4*>(w + (size_t)row * 784)[t];
        ushort4 h, l;
        h.x = bf16_rne(v.x); h.y = bf16_rne(v.y); h.z = bf16_rne(v.z); h.w = bf16_rne(v.w);
        float4 hf = make_float4(__uint_as_float((unsigned)h.x << 16),
                                __uint_as_float((unsigned)h.y << 16),
                                __uint_as_float((unsigned)h.z << 16),
                                __uint_as_float((unsigned)h.w << 16));
        l.x = bf16_rne(v.x - hf.x); l.y = bf16_rne(v.y - hf.y);
        l.z = bf16_rne(v.z - hf.z); l.w = bf16_rne(v.w - hf.w);
        reinterpret_cast<ushort4*>(whi + (size_t)row * 800)[t] = h;
        reinterpret_cast<ushort4*>(wlo + (size_t)row * 800)[t] = l;
    } else if (t < 200) {
        const ushort4 z = make_ushort4(0, 0, 0, 0);
        reinterpret_cast<ushort4*>(whi + (size_t)row * 800)[t] = z;
        reinterpret_cast<ushort4*>(wlo + (size_t)row * 800)[t] = z;
    }
}

// ---------------- Kernel A: split-bf16 MFMA GEMM  *** PROBE x4 *** ----------
// K-loop runs 4x (acc accumulates, scaled 0.25 at end -> no DCE);
// f64 stat atomics issued 4x with 0.25 scale (measures contention cost).
__global__ __launch_bounds__(256) void gemm1_mfma_stats(
    const float* __restrict__ x,
    const ushort* __restrict__ whi, const ushort* __restrict__ wlo,
    const float* __restrict__ b, float* __restrict__ o1,
    double* __restrict__ sums, double* __restrict__ sumsq)
{
    const int t    = threadIdx.x;
    const int lane = t & 63;
    const int wid  = blockIdx.x * 4 + (t >> 6);
    const int rt   = wid >> 3;
    const int ct   = wid & 7;
    const int lr   = lane & 15;
    const int lk   = lane >> 4;

    const float*  px  = x   + (size_t)(rt * 16 + lr) * 784 + lk * 8;
    const ushort* pbh = whi + (size_t)(ct * 16 + lr) * 800 + lk * 8;
    const ushort* pbl = wlo + (size_t)(ct * 16 + lr) * 800 + lk * 8;

    floatx4 acc = {};
#pragma unroll 1
    for (int rep = 0; rep < 4; ++rep) {
#pragma unroll 2
        for (int k0 = 0; k0 < 768; k0 += 32) {
            bf16x8 ahi, alo;
            cvt8(px + k0, ahi, alo);
            bf16x8 bhi = *reinterpret_cast<const bf16x8*>(pbh + k0);
            bf16x8 blo = *reinterpret_cast<const bf16x8*>(pbl + k0);
            acc = __builtin_amdgcn_mfma_f32_16x16x32_bf16(alo, bhi, acc, 0, 0, 0);
            acc = __builtin_amdgcn_mfma_f32_16x16x32_bf16(ahi, blo, acc, 0, 0, 0);
            acc = __builtin_amdgcn_mfma_f32_16x16x32_bf16(ahi, bhi, acc, 0, 0, 0);
        }
        {   // peeled K tail (k0 = 768)
            bf16x8 ahi = {}, alo = {};
            if (lk < 2) cvt8(px + 768, ahi, alo);
            bf16x8 bhi = *reinterpret_cast<const bf16x8*>(pbh + 768);
            bf16x8 blo = *reinterpret_cast<const bf16x8*>(pbl + 768);
            acc = __builtin_amdgcn_mfma_f32_16x16x32_bf16(alo, bhi, acc, 0, 0, 0);
            acc = __builtin_amdgcn_mfma_f32_16x16x32_bf16(ahi, blo, acc, 0, 0, 0);
            acc = __builtin_amdgcn_mfma_f32_16x16x32_bf16(ahi, bhi, acc, 0, 0, 0);
        }
    }

    const int col = ct * 16 + lr;
    const float bias = b[col];
    float s = 0.f, s2 = 0.f;
#pragma unroll
    for (int j = 0; j < 4; ++j) {
        const int row = rt * 16 + lk * 4 + j;
        const float val = selu(acc[j] * 0.25f + bias);
        o1[(size_t)row * 128 + col] = val;
        s += val;
        s2 = fmaf(val, val, s2);
    }
    s  += __shfl_xor(s, 16);   s  += __shfl_xor(s, 32);
    s2 += __shfl_xor(s2, 16);  s2 += __shfl_xor(s2, 32);
#pragma unroll 1
    for (int rep = 0; rep < 4; ++rep) {
        if (lane < 16) {
            atomicAdd(&sums[col],  (double)(s  * 0.25f));
            atomicAdd(&sumsq[col], (double)(s2 * 0.25f));
        }
    }
}

// ---------------- Kernel C: BN + fc2 + selu  *** PROBE x8 *** ---------------
__global__ __launch_bounds__(256) void bn_fc2_selu(
    const float* __restrict__ o1, const double* __restrict__ sums, const double* __restrict__ sumsq,
    const float* __restrict__ gamma, const float* __restrict__ beta,
    const float* __restrict__ fc2w, const float* __restrict__ fc2b,
    float* __restrict__ o_out, float4* __restrict__ packed)
{
    const int wave = threadIdx.x >> 6;
    const int lane = threadIdx.x & 63;
    const int row  = blockIdx.x * 4 + wave;

#pragma unroll 1
    for (int rep = 0; rep < 8; ++rep) {
        float d0 = 0.f, d1 = 0.f;
#pragma unroll
        for (int half = 0; half < 2; ++half) {
            const int col = lane + half * 64;
            const float mu  = (float)(sums[col]  * (1.0 / 8192.0));
            const float ex2 = (float)(sumsq[col] * (1.0 / 8192.0));
            const float var = ex2 - mu * mu;
            const float inv = rsqrtf(var + 1e-5f);
            const float v = (o1[(size_t)row * 128 + col] - mu) * inv * gamma[col] + beta[col];
            d0 = fmaf(v, fc2w[col],       d0);
            d1 = fmaf(v, fc2w[128 + col], d1);
        }
#pragma unroll
        for (int off = 32; off >= 1; off >>= 1) {
            d0 += __shfl_down(d0, off);
            d1 += __shfl_down(d1, off);
        }
        if (lane == 0) {
            const float y0 = selu(d0 + fc2b[0]);
            const float y1 = selu(d1 + fc2b[1]);
            o_out[(size_t)row * 2 + 0] = y0;
            o_out[(size_t)row * 2 + 1] = y1;
            packed[row] = make_float4(y0, y1, y0 * y0 + y1 * y1, 0.f);
        }
    }
}

// ---------------- Kernel D: denom reduce  *** PROBE x4 *** ------------------
__global__ __launch_bounds__(256) void denom_reduce(
    const float4* __restrict__ packed, double* __restrict__ denom)
{
    const int rb = blockIdx.x * 64;
    const int cb = blockIdx.y * 1024;
    if (cb + 1024 <= rb) return;
    const int t = threadIdx.x;
    const bool full = (cb >= rb + 64);

    float4 cd[4];
#pragma unroll
    for (int u = 0; u < 4; ++u) cd[u] = packed[cb + t + u * 256];

    float accf = 0.f;
#pragma unroll 1
    for (int rep = 0; rep < 4; ++rep) {
#pragma unroll 4
        for (int r = 0; r < 64; ++r) {
            const int i = rb + r;
            const float4 pi = packed[i];
#pragma unroll
            for (int u = 0; u < 4; ++u) {
                float dis = pi.z + cd[u].z - 2.f * fmaf(pi.x, cd[u].x, pi.y * cd[u].y);
                dis = fmaxf(dis, 0.f);
                float f = fast_rcp(1.f + dis);
                if (!full) {
                    const int j = cb + t + u * 256;
                    f = (j > i) ? f : 0.f;
                }
                accf += f;
            }
        }
    }
#pragma unroll
    for (int off = 32; off >= 1; off >>= 1) accf += __shfl_down(accf, off);
    __shared__ double wsum[4];
    const int wave = t >> 6, lane = t & 63;
    if (lane == 0) wsum[wave] = (double)accf;
    __syncthreads();
    if (t == 0) atomicAdd(denom, 2.0 * 0.25 * (wsum[0] + wsum[1] + wsum[2] + wsum[3]));
}

// ---------------- Kernel E: qij write, slab layout (x1, known 38.8 us) ------
__global__ __launch_bounds__(512) void qij_write_slab(
    const float4* __restrict__ packed, const double* __restrict__ denom,
    float* __restrict__ qij)
{
    const int t  = threadIdx.x;              // 0..511
    const int rb = blockIdx.x * 16;
    const float inv = (float)(1.0 / denom[0]);

    float4 cd[4][4];
#pragma unroll
    for (int c = 0; c < 4; ++c)
#pragma unroll
        for (int u = 0; u < 4; ++u)
            cd[c][u] = packed[c * 2048 + t * 4 + u];

#pragma unroll 2
    for (int r = 0; r < 16; ++r) {
        const int j = rb + r;
        const float4 pi = packed[j];
        float* outrow = qij + (size_t)j * 8192 + t * 4;
#pragma unroll
        for (int c = 0; c < 4; ++c) {
            floatx4 q;
#pragma unroll
            for (int u = 0; u < 4; ++u) {
                float dis = pi.z + cd[c][u].z
                          - 2.f * fmaf(pi.x, cd[c][u].x, pi.y * cd[c][u].y);
                dis = fmaxf(dis, 0.f);
                q[u] = inv * fast_rcp(1.f + dis);
            }
            *reinterpret_cast<floatx4*>(outrow + c * 2048) = q;
        }
    }
}

// ---------------------------------------------------------------------------
extern "C" void kernel_launch(void* const* d_in, const int* in_sizes, int n_in,
                              void* d_out, int out_size, void* d_ws, size_t ws_size,
                              hipStream_t stream)
{
    const float* x      = (const float*)d_in[0];
    const float* fc_w   = (const float*)d_in[1];
    const float* fc_b   = (const float*)d_in[2];
    const float* gamma  = (const float*)d_in[3];
    const float* beta   = (const float*)d_in[4];
    const float* fc2_w  = (const float*)d_in[5];
    const float* fc2_b  = (const float*)d_in[6];

    constexpr int N = 8192;

    float* qij   = (float*)d_out;                          // [N, N]
    float* o_out = (float*)d_out + (size_t)N * N;          // [N, 2]

    char* ws = (char*)d_ws;
    constexpr size_t O1_OFF     = 0;                          // 4 MB
    constexpr size_t ACC_OFF    = (size_t)N * 128 * 4;        // 257 doubles
    constexpr size_t PACKED_OFF = ACC_OFF + 4096;             // 128 KB
    constexpr size_t WHI_OFF    = PACKED_OFF + (size_t)N * 16;
    constexpr size_t WPLANE     = ((size_t)128 * 800 * 2 + 63) / 64 * 64;
    constexpr size_t WLO_OFF    = WHI_OFF + WPLANE;

    float*  o1     = (float*)(ws + O1_OFF);
    double* accs   = (double*)(ws + ACC_OFF);              // sums|sumsq|denom
    double* sums   = accs;
    double* sumsq  = accs + 128;
    double* denom  = accs + 256;
    float4* packed = (float4*)(ws + PACKED_OFF);
    ushort* whi    = (ushort*)(ws + WHI_OFF);
    ushort* wlo    = (ushort*)(ws + WLO_OFF);

    // W: convert fc_w to bf16 hi/lo planes, zero accs
    convert_w_pad<<<128, 256, 0, stream>>>(fc_w, whi, wlo, accs);

    // A: GEMM + stats  [x4 probe: K-loop and atomics]
    gemm1_mfma_stats<<<1024, 256, 0, stream>>>(x, whi, wlo, fc_b, o1, sums, sumsq);

    // C: BN + fc2  [x8 probe]
    bn_fc2_selu<<<N / 4, 256, 0, stream>>>(o1, sums, sumsq, gamma, beta, fc2_w, fc2_b, o_out, packed);

    // D: denom  [x4 probe]
    denom_reduce<<<dim3(N / 64, N / 1024), 256, 0, stream>>>(packed, denom);

    // E: qij write (known: 38.8 us, at write floor)
    qij_write_slab<<<512, 512, 0, stream>>>(packed, denom, qij);
}

// Round 15
// 135.746 us; speedup vs baseline: 2.0769x; 2.0769x over previous
//
#include <hip/hip_runtime.h>
#include <hip/hip_bf16.h>

#define SELU_L 1.0507009873554805f
#define SELU_A 1.6732632423543772f

typedef float  floatx4 __attribute__((ext_vector_type(4)));
typedef short  bf16x8  __attribute__((ext_vector_type(8)));

__device__ __forceinline__ float selu(float x) {
    return x > 0.f ? SELU_L * x : SELU_L * SELU_A * (expf(x) - 1.f);
}
__device__ __forceinline__ float fast_rcp(float x) {
    return __builtin_amdgcn_rcpf(x);
}
__device__ __forceinline__ unsigned short bf16_rne(float f) {
    unsigned int u = __float_as_uint(f);
    u += 0x7fffu + ((u >> 16) & 1u);
    return (unsigned short)(u >> 16);
}
__device__ __forceinline__ void cvt4(const float4 v, ushort4& h, ushort4& l) {
    h.x = bf16_rne(v.x); h.y = bf16_rne(v.y); h.z = bf16_rne(v.z); h.w = bf16_rne(v.w);
    float4 hf = make_float4(__uint_as_float((unsigned)h.x << 16),
                            __uint_as_float((unsigned)h.y << 16),
                            __uint_as_float((unsigned)h.z << 16),
                            __uint_as_float((unsigned)h.w << 16));
    l.x = bf16_rne(v.x - hf.x); l.y = bf16_rne(v.y - hf.y);
    l.z = bf16_rne(v.z - hf.z); l.w = bf16_rne(v.w - hf.w);
}

// ---------------- Kernel W: convert fc_w into bf16 hi/lo planes -------------
// Also zeroes the 32-sharded stat accumulators + denom.
__global__ __launch_bounds__(256) void convert_w_pad(
    const float* __restrict__ w, ushort* __restrict__ whi, ushort* __restrict__ wlo,
    double* __restrict__ shards, double* __restrict__ accs)
{
    const int row = blockIdx.x;           // 0..127
    const int t   = threadIdx.x;
    if (t < 64) shards[(size_t)row * 64 + t] = 0.0;   // 128*64 = 8192 doubles
    if (row == 0 && t == 64) accs[256] = 0.0;         // denom
    if (t < 196) {
        float4 v = reinterpret_cast<const float4*>(w + (size_t)row * 784)[t];
        ushort4 h, l;
        cvt4(v, h, l);
        reinterpret_cast<ushort4*>(whi + (size_t)row * 800)[t] = h;
        reinterpret_cast<ushort4*>(wlo + (size_t)row * 800)[t] = l;
    } else if (t < 200) {
        const ushort4 z = make_ushort4(0, 0, 0, 0);
        reinterpret_cast<ushort4*>(whi + (size_t)row * 800)[t] = z;
        reinterpret_cast<ushort4*>(wlo + (size_t)row * 800)[t] = z;
    }
}

// ---------------- Kernel A: LDS-staged split-bf16 MFMA GEMM -----------------
// 256 blocks x 256 threads. Block stages 32 x-rows into LDS (coalesced 1KB
// wave reads, cvt to hi/lo bf16 at stage time), then 4 waves compute:
// wave w -> row-tile (w&1) x col-group (w>>1) = 16 rows x 64 cols.
// Stats: 32-sharded f64 atomics (contention 512 -> 16 per address).
#define LROW 824   // ushorts per LDS row (784 data + 16 zero-pad + bank slack)
__global__ __launch_bounds__(256) void gemm1_lds_stats(
    const float* __restrict__ x,
    const ushort* __restrict__ whi, const ushort* __restrict__ wlo,
    const float* __restrict__ b, float* __restrict__ o1,
    double* __restrict__ shards)
{
    __shared__ ushort hi_lds[32 * LROW];
    __shared__ ushort lo_lds[32 * LROW];

    const int t    = threadIdx.x;
    const int wv   = t >> 6;
    const int lane = t & 63;
    const int rowbase = blockIdx.x * 32;

    // ---- stage: wave wv loads rows wv*8 .. wv*8+7, contiguous 1KB per inst
#pragma unroll 2
    for (int r8 = 0; r8 < 8; ++r8) {
        const int r = wv * 8 + r8;
        const float* src = x + (size_t)(rowbase + r) * 784;
        ushort* hrow = hi_lds + r * LROW;
        ushort* lrow = lo_lds + r * LROW;
#pragma unroll
        for (int s = 0; s < 3; ++s) {
            float4 v = *reinterpret_cast<const float4*>(src + s * 256 + lane * 4);
            ushort4 h, l;
            cvt4(v, h, l);
            *reinterpret_cast<ushort4*>(hrow + s * 256 + lane * 4) = h;
            *reinterpret_cast<ushort4*>(lrow + s * 256 + lane * 4) = l;
        }
        if (lane < 4) {                       // K tail: floats 768..783
            float4 v = *reinterpret_cast<const float4*>(src + 768 + lane * 4);
            ushort4 h, l;
            cvt4(v, h, l);
            *reinterpret_cast<ushort4*>(hrow + 768 + lane * 4) = h;
            *reinterpret_cast<ushort4*>(lrow + 768 + lane * 4) = l;
        } else if (lane < 8) {                // zero-pad cols 784..799
            const ushort4 z = make_ushort4(0, 0, 0, 0);
            *reinterpret_cast<ushort4*>(hrow + 784 + (lane - 4) * 4) = z;
            *reinterpret_cast<ushort4*>(lrow + 784 + (lane - 4) * 4) = z;
        }
    }
    __syncthreads();

    // ---- compute
    const int rt2 = wv & 1;
    const int cg  = wv >> 1;
    const int lr  = lane & 15;
    const int lk  = lane >> 4;

    const ushort* arow_h = hi_lds + (rt2 * 16 + lr) * LROW + lk * 8;
    const ushort* arow_l = lo_lds + (rt2 * 16 + lr) * LROW + lk * 8;
    const ushort* pbh[4];
    const ushort* pbl[4];
#pragma unroll
    for (int c = 0; c < 4; ++c) {
        const int wrow = (cg * 4 + c) * 16 + lr;
        pbh[c] = whi + (size_t)wrow * 800 + lk * 8;
        pbl[c] = wlo + (size_t)wrow * 800 + lk * 8;
    }

    floatx4 acc[4] = {};
#pragma unroll 1
    for (int k0 = 0; k0 < 800; k0 += 32) {
        bf16x8 ahi = *reinterpret_cast<const bf16x8*>(arow_h + k0);
        bf16x8 alo = *reinterpret_cast<const bf16x8*>(arow_l + k0);
#pragma unroll
        for (int c = 0; c < 4; ++c) {
            bf16x8 bhi = *reinterpret_cast<const bf16x8*>(pbh[c] + k0);
            bf16x8 blo = *reinterpret_cast<const bf16x8*>(pbl[c] + k0);
            acc[c] = __builtin_amdgcn_mfma_f32_16x16x32_bf16(alo, bhi, acc[c], 0, 0, 0);
            acc[c] = __builtin_amdgcn_mfma_f32_16x16x32_bf16(ahi, blo, acc[c], 0, 0, 0);
            acc[c] = __builtin_amdgcn_mfma_f32_16x16x32_bf16(ahi, bhi, acc[c], 0, 0, 0);
        }
    }

    // ---- epilogue: bias + selu + o1 store + sharded column stats
    const int shard = blockIdx.x & 31;
#pragma unroll
    for (int c = 0; c < 4; ++c) {
        const int col = (cg * 4 + c) * 16 + lr;
        const float bias = b[col];
        float s = 0.f, s2 = 0.f;
#pragma unroll
        for (int j = 0; j < 4; ++j) {
            const int row = rowbase + rt2 * 16 + lk * 4 + j;
            const float val = selu(acc[c][j] + bias);
            o1[(size_t)row * 128 + col] = val;
            s += val;
            s2 = fmaf(val, val, s2);
        }
        s  += __shfl_xor(s, 16);   s  += __shfl_xor(s, 32);
        s2 += __shfl_xor(s2, 16);  s2 += __shfl_xor(s2, 32);
        if (lane < 16) {
            atomicAdd(&shards[(size_t)shard * 128 + col],            (double)s);
            atomicAdd(&shards[4096 + (size_t)shard * 128 + col],     (double)s2);
        }
    }
}

// ---------------- Kernel R: fold 32 shards -> sums / sumsq ------------------
__global__ __launch_bounds__(256) void reduce_stats(
    const double* __restrict__ shards, double* __restrict__ accs)
{
    const int t = threadIdx.x;            // which = t>>7 (0:sums 1:sumsq)
    const int which = t >> 7, col = t & 127;
    const double* p = shards + (size_t)which * 4096 + col;
    double a = 0.0;
#pragma unroll
    for (int s = 0; s < 32; ++s) a += p[s * 128];
    accs[which * 128 + col] = a;
}

// ---------------- Kernel C: BN normalize + fc2 + selu -----------------------
__global__ __launch_bounds__(256) void bn_fc2_selu(
    const float* __restrict__ o1, const double* __restrict__ sums, const double* __restrict__ sumsq,
    const float* __restrict__ gamma, const float* __restrict__ beta,
    const float* __restrict__ fc2w, const float* __restrict__ fc2b,
    float* __restrict__ o_out, float4* __restrict__ packed)
{
    const int wave = threadIdx.x >> 6;
    const int lane = threadIdx.x & 63;
    const int row  = blockIdx.x * 4 + wave;

    float d0 = 0.f, d1 = 0.f;
#pragma unroll
    for (int half = 0; half < 2; ++half) {
        const int col = lane + half * 64;
        const float mu  = (float)(sums[col]  * (1.0 / 8192.0));
        const float ex2 = (float)(sumsq[col] * (1.0 / 8192.0));
        const float var = ex2 - mu * mu;
        const float inv = rsqrtf(var + 1e-5f);
        const float v = (o1[(size_t)row * 128 + col] - mu) * inv * gamma[col] + beta[col];
        d0 = fmaf(v, fc2w[col],       d0);
        d1 = fmaf(v, fc2w[128 + col], d1);
    }
#pragma unroll
    for (int off = 32; off >= 1; off >>= 1) {
        d0 += __shfl_down(d0, off);
        d1 += __shfl_down(d1, off);
    }
    if (lane == 0) {
        const float y0 = selu(d0 + fc2b[0]);
        const float y1 = selu(d1 + fc2b[1]);
        o_out[(size_t)row * 2 + 0] = y0;
        o_out[(size_t)row * 2 + 1] = y1;
        packed[row] = make_float4(y0, y1, y0 * y0 + y1 * y1, 0.f);
    }
}

// ---------------- Kernel D: denom = 2 * sum_{i<j} 1/(1+dis) -----------------
__global__ __launch_bounds__(256) void denom_reduce(
    const float4* __restrict__ packed, double* __restrict__ denom)
{
    const int rb = blockIdx.x * 64;
    const int cb = blockIdx.y * 1024;
    if (cb + 1024 <= rb) return;
    const int t = threadIdx.x;
    const bool full = (cb >= rb + 64);

    float4 cd[4];
#pragma unroll
    for (int u = 0; u < 4; ++u) cd[u] = packed[cb + t + u * 256];

    float accf = 0.f;
#pragma unroll 4
    for (int r = 0; r < 64; ++r) {
        const int i = rb + r;
        const float4 pi = packed[i];
#pragma unroll
        for (int u = 0; u < 4; ++u) {
            float dis = pi.z + cd[u].z - 2.f * fmaf(pi.x, cd[u].x, pi.y * cd[u].y);
            dis = fmaxf(dis, 0.f);
            float f = fast_rcp(1.f + dis);
            if (!full) {
                const int j = cb + t + u * 256;
                f = (j > i) ? f : 0.f;
            }
            accf += f;
        }
    }
#pragma unroll
    for (int off = 32; off >= 1; off >>= 1) accf += __shfl_down(accf, off);
    __shared__ double wsum[4];
    const int wave = t >> 6, lane = t & 63;
    if (lane == 0) wsum[wave] = (double)accf;
    __syncthreads();
    if (t == 0) atomicAdd(denom, 2.0 * (wsum[0] + wsum[1] + wsum[2] + wsum[3]));
}

// ---------------- Kernel E: qij write, slab layout (at write floor) ---------
__global__ __launch_bounds__(512) void qij_write_slab(
    const float4* __restrict__ packed, const double* __restrict__ denom,
    float* __restrict__ qij)
{
    const int t  = threadIdx.x;              // 0..511
    const int rb = blockIdx.x * 16;
    const float inv = (float)(1.0 / denom[0]);

    float4 cd[4][4];
#pragma unroll
    for (int c = 0; c < 4; ++c)
#pragma unroll
        for (int u = 0; u < 4; ++u)
            cd[c][u] = packed[c * 2048 + t * 4 + u];

#pragma unroll 2
    for (int r = 0; r < 16; ++r) {
        const int j = rb + r;
        const float4 pi = packed[j];
        float* outrow = qij + (size_t)j * 8192 + t * 4;
#pragma unroll
        for (int c = 0; c < 4; ++c) {
            floatx4 q;
#pragma unroll
            for (int u = 0; u < 4; ++u) {
                float dis = pi.z + cd[c][u].z
                          - 2.f * fmaf(pi.x, cd[c][u].x, pi.y * cd[c][u].y);
                dis = fmaxf(dis, 0.f);
                q[u] = inv * fast_rcp(1.f + dis);
            }
            *reinterpret_cast<floatx4*>(outrow + c * 2048) = q;
        }
    }
}

// ---------------------------------------------------------------------------
extern "C" void kernel_launch(void* const* d_in, const int* in_sizes, int n_in,
                              void* d_out, int out_size, void* d_ws, size_t ws_size,
                              hipStream_t stream)
{
    const float* x      = (const float*)d_in[0];
    const float* fc_w   = (const float*)d_in[1];
    const float* fc_b   = (const float*)d_in[2];
    const float* gamma  = (const float*)d_in[3];
    const float* beta   = (const float*)d_in[4];
    const float* fc2_w  = (const float*)d_in[5];
    const float* fc2_b  = (const float*)d_in[6];

    constexpr int N = 8192;

    float* qij   = (float*)d_out;                          // [N, N]
    float* o_out = (float*)d_out + (size_t)N * N;          // [N, 2]

    char* ws = (char*)d_ws;
    constexpr size_t O1_OFF     = 0;                          // 4 MB
    constexpr size_t ACC_OFF    = (size_t)N * 128 * 4;        // 257 doubles
    constexpr size_t SH_OFF     = ACC_OFF + 4096;             // 8192 doubles = 64 KB
    constexpr size_t PACKED_OFF = SH_OFF + 65536;             // 128 KB
    constexpr size_t WHI_OFF    = PACKED_OFF + (size_t)N * 16;
    constexpr size_t WPLANE     = ((size_t)128 * 800 * 2 + 63) / 64 * 64;
    constexpr size_t WLO_OFF    = WHI_OFF + WPLANE;

    float*  o1     = (float*)(ws + O1_OFF);
    double* accs   = (double*)(ws + ACC_OFF);              // sums|sumsq|denom
    double* sums   = accs;
    double* sumsq  = accs + 128;
    double* denom  = accs + 256;
    double* shards = (double*)(ws + SH_OFF);               // [2][32][128]
    float4* packed = (float4*)(ws + PACKED_OFF);
    ushort* whi    = (ushort*)(ws + WHI_OFF);
    ushort* wlo    = (ushort*)(ws + WLO_OFF);

    // W: convert fc_w to bf16 hi/lo planes, zero shards + denom
    convert_w_pad<<<128, 256, 0, stream>>>(fc_w, whi, wlo, shards, accs);

    // A: LDS-staged split-bf16 MFMA GEMM + sharded stats
    gemm1_lds_stats<<<256, 256, 0, stream>>>(x, whi, wlo, fc_b, o1, shards);

    // R: fold shards -> sums / sumsq
    reduce_stats<<<1, 256, 0, stream>>>(shards, accs);

    // C: normalize + fc2 + selu -> o_out, packed
    bn_fc2_selu<<<N / 4, 256, 0, stream>>>(o1, sums, sumsq, gamma, beta, fc2_w, fc2_b, o_out, packed);

    // D: denom = 2 * sum_{i<j} 1/(1+dis)
    denom_reduce<<<dim3(N / 64, N / 1024), 256, 0, stream>>>(packed, denom);

    // E: qij = (1/denom) / (1 + dis)
    qij_write_slab<<<512, 512, 0, stream>>>(packed, denom, qij);
}

// Round 16
// 109.872 us; speedup vs baseline: 2.5660x; 1.2355x over previous
//
#include <hip/hip_runtime.h>
#include <hip/hip_bf16.h>

#define SELU_L 1.0507009873554805f
#define SELU_A 1.6732632423543772f

typedef float  floatx4 __attribute__((ext_vector_type(4)));
typedef short  bf16x8  __attribute__((ext_vector_type(8)));

__device__ __forceinline__ float selu(float x) {
    return x > 0.f ? SELU_L * x : SELU_L * SELU_A * (expf(x) - 1.f);
}
__device__ __forceinline__ float fast_rcp(float x) {
    return __builtin_amdgcn_rcpf(x);
}
__device__ __forceinline__ unsigned short bf16_rne(float f) {
    unsigned int u = __float_as_uint(f);
    u += 0x7fffu + ((u >> 16) & 1u);
    return (unsigned short)(u >> 16);
}
__device__ __forceinline__ void cvt8v(const float4 v0, const float4 v1,
                                      bf16x8& h8, bf16x8& l8) {
    float f[8] = {v0.x, v0.y, v0.z, v0.w, v1.x, v1.y, v1.z, v1.w};
#pragma unroll
    for (int j = 0; j < 8; ++j) {
        const unsigned short h = bf16_rne(f[j]);
        const float hf = __uint_as_float((unsigned)h << 16);
        const unsigned short l = bf16_rne(f[j] - hf);
        h8[j] = (short)h;
        l8[j] = (short)l;
    }
}

// ---------------- Kernel W: convert fc_w into bf16 hi/lo planes (K->832) ----
// whi/wlo: [128][832] ushort, cols 784..831 zero. Zeroes shards + denom.
__global__ __launch_bounds__(256) void convert_w_pad(
    const float* __restrict__ w, ushort* __restrict__ whi, ushort* __restrict__ wlo,
    double* __restrict__ shards, double* __restrict__ accs)
{
    const int row = blockIdx.x;           // 0..127
    const int t   = threadIdx.x;
    if (t < 64) shards[(size_t)row * 64 + t] = 0.0;   // 8192 doubles total
    if (row == 0 && t == 64) accs[256] = 0.0;         // denom
    if (t < 196) {
        float4 v = reinterpret_cast<const float4*>(w + (size_t)row * 784)[t];
        ushort4 h, l;
        h.x = bf16_rne(v.x); h.y = bf16_rne(v.y); h.z = bf16_rne(v.z); h.w = bf16_rne(v.w);
        float4 hf = make_float4(__uint_as_float((unsigned)h.x << 16),
                                __uint_as_float((unsigned)h.y << 16),
                                __uint_as_float((unsigned)h.z << 16),
                                __uint_as_float((unsigned)h.w << 16));
        l.x = bf16_rne(v.x - hf.x); l.y = bf16_rne(v.y - hf.y);
        l.z = bf16_rne(v.z - hf.z); l.w = bf16_rne(v.w - hf.w);
        reinterpret_cast<ushort4*>(whi + (size_t)row * 832)[t] = h;
        reinterpret_cast<ushort4*>(wlo + (size_t)row * 832)[t] = l;
    } else if (t < 208) {                 // zero-pad cols 784..831
        const ushort4 z = make_ushort4(0, 0, 0, 0);
        reinterpret_cast<ushort4*>(whi + (size_t)row * 832)[t] = z;
        reinterpret_cast<ushort4*>(wlo + (size_t)row * 832)[t] = z;
    }
}

// ---------------- Kernel A: BK-tiled LDS MFMA GEMM --------------------------
// Block 64x64 output tile, 4 waves (wave = 32x32 via 2x2 16x16 tiles).
// BK=64 chunks; A and B both staged in LDS as bf16 hi/lo (36 KB total).
// Register prefetch of next chunk overlaps compute. 8 LDS reads / 12 MFMA.
#define AP 72   // padded ushorts per 64-k row: 144 B, 16B-aligned, even banks
__global__ __launch_bounds__(256) void gemm1_tiled_stats(
    const float* __restrict__ x,
    const ushort* __restrict__ whi, const ushort* __restrict__ wlo,
    const float* __restrict__ b, float* __restrict__ o1,
    double* __restrict__ shards)
{
    __shared__ ushort ah[64 * AP], al[64 * AP];
    __shared__ ushort bh[64 * AP], bl[64 * AP];

    const int t    = threadIdx.x;
    const int wv   = t >> 6;
    const int lane = t & 63;
    const int lr   = lane & 15;
    const int lk   = lane >> 4;
    const int rowbase = blockIdx.x * 64;
    const int colbase = blockIdx.y * 64;

    // staging assignments
    const int arow = t >> 2, ahalf = t & 3;     // x: row, 16-float segment
    const int bcol = t >> 2, bq    = t & 3;     // w: col, 16-ush segment
    const float*  xsrc = x + (size_t)(rowbase + arow) * 784;
    const ushort* bhsrc = whi + (size_t)(colbase + bcol) * 832 + bq * 16;
    const ushort* blsrc = wlo + (size_t)(colbase + bcol) * 832 + bq * 16;

    // prefetch regs
    float4 xr[4];
    uint4  bhr[2], blr[2];

    auto load_chunk = [&](int kc) {
        const int gk = kc * 64 + ahalf * 16;
        if (gk < 784) {
#pragma unroll
            for (int i = 0; i < 4; ++i)
                xr[i] = *reinterpret_cast<const float4*>(xsrc + gk + i * 4);
        } else {
            const float4 z = make_float4(0.f, 0.f, 0.f, 0.f);
#pragma unroll
            for (int i = 0; i < 4; ++i) xr[i] = z;
        }
        const int bk = kc * 64;
        bhr[0] = *reinterpret_cast<const uint4*>(bhsrc + bk);
        bhr[1] = *reinterpret_cast<const uint4*>(bhsrc + bk + 8);
        blr[0] = *reinterpret_cast<const uint4*>(blsrc + bk);
        blr[1] = *reinterpret_cast<const uint4*>(blsrc + bk + 8);
    };

    auto store_chunk = [&]() {
        bf16x8 h0, l0, h1, l1;
        cvt8v(xr[0], xr[1], h0, l0);
        cvt8v(xr[2], xr[3], h1, l1);
        ushort* ad = ah + arow * AP + ahalf * 16;
        ushort* ld = al + arow * AP + ahalf * 16;
        *reinterpret_cast<bf16x8*>(ad)     = h0;
        *reinterpret_cast<bf16x8*>(ad + 8) = h1;
        *reinterpret_cast<bf16x8*>(ld)     = l0;
        *reinterpret_cast<bf16x8*>(ld + 8) = l1;
        ushort* bd = bh + bcol * AP + bq * 16;
        ushort* le = bl + bcol * AP + bq * 16;
        *reinterpret_cast<uint4*>(bd)     = bhr[0];
        *reinterpret_cast<uint4*>(bd + 8) = bhr[1];
        *reinterpret_cast<uint4*>(le)     = blr[0];
        *reinterpret_cast<uint4*>(le + 8) = blr[1];
    };

    floatx4 acc[2][2] = {};
    const int rbase = (wv & 1) * 32;            // wave's row-half in tile
    const int cbase = (wv >> 1) * 32;           // wave's col-half in tile

    load_chunk(0);
    for (int kc = 0; kc < 13; ++kc) {
        __syncthreads();                        // LDS free from prev reads
        store_chunk();
        if (kc < 12) load_chunk(kc + 1);        // prefetch overlaps barrier+compute
        __syncthreads();

#pragma unroll
        for (int s = 0; s < 2; ++s) {
            bf16x8 Ah[2], Al[2], Bh[2], Bl[2];
#pragma unroll
            for (int rt = 0; rt < 2; ++rt) {
                const int off = (rbase + rt * 16 + lr) * AP + s * 32 + lk * 8;
                Ah[rt] = *reinterpret_cast<const bf16x8*>(ah + off);
                Al[rt] = *reinterpret_cast<const bf16x8*>(al + off);
            }
#pragma unroll
            for (int ct = 0; ct < 2; ++ct) {
                const int off = (cbase + ct * 16 + lr) * AP + s * 32 + lk * 8;
                Bh[ct] = *reinterpret_cast<const bf16x8*>(bh + off);
                Bl[ct] = *reinterpret_cast<const bf16x8*>(bl + off);
            }
#pragma unroll
            for (int rt = 0; rt < 2; ++rt)
#pragma unroll
                for (int ct = 0; ct < 2; ++ct) {
                    acc[rt][ct] = __builtin_amdgcn_mfma_f32_16x16x32_bf16(Al[rt], Bh[ct], acc[rt][ct], 0, 0, 0);
                    acc[rt][ct] = __builtin_amdgcn_mfma_f32_16x16x32_bf16(Ah[rt], Bl[ct], acc[rt][ct], 0, 0, 0);
                    acc[rt][ct] = __builtin_amdgcn_mfma_f32_16x16x32_bf16(Ah[rt], Bh[ct], acc[rt][ct], 0, 0, 0);
                }
        }
    }

    // epilogue: bias + selu + o1 + sharded stats
    const int shard = (blockIdx.x * 2 + blockIdx.y) & 31;
#pragma unroll
    for (int ct = 0; ct < 2; ++ct) {
        const int col = colbase + cbase + ct * 16 + lr;
        const float bias = b[col];
        float s = 0.f, s2 = 0.f;
#pragma unroll
        for (int rt = 0; rt < 2; ++rt) {
#pragma unroll
            for (int j = 0; j < 4; ++j) {
                const int row = rowbase + rbase + rt * 16 + lk * 4 + j;
                const float val = selu(acc[rt][ct][j] + bias);
                o1[(size_t)row * 128 + col] = val;
                s += val;
                s2 = fmaf(val, val, s2);
            }
        }
        s  += __shfl_xor(s, 16);   s  += __shfl_xor(s, 32);
        s2 += __shfl_xor(s2, 16);  s2 += __shfl_xor(s2, 32);
        if (lane < 16) {
            atomicAdd(&shards[(size_t)shard * 128 + col],        (double)s);
            atomicAdd(&shards[4096 + (size_t)shard * 128 + col], (double)s2);
        }
    }
}

// ---------------- Kernel R: fold 32 shards -> sums / sumsq ------------------
__global__ __launch_bounds__(256) void reduce_stats(
    const double* __restrict__ shards, double* __restrict__ accs)
{
    const int t = threadIdx.x;
    const int which = t >> 7, col = t & 127;
    const double* p = shards + (size_t)which * 4096 + col;
    double a = 0.0;
#pragma unroll
    for (int s = 0; s < 32; ++s) a += p[s * 128];
    accs[which * 128 + col] = a;
}

// ---------------- Kernel C: BN normalize + fc2 + selu -----------------------
__global__ __launch_bounds__(256) void bn_fc2_selu(
    const float* __restrict__ o1, const double* __restrict__ sums, const double* __restrict__ sumsq,
    const float* __restrict__ gamma, const float* __restrict__ beta,
    const float* __restrict__ fc2w, const float* __restrict__ fc2b,
    float* __restrict__ o_out, float4* __restrict__ packed)
{
    const int wave = threadIdx.x >> 6;
    const int lane = threadIdx.x & 63;
    const int row  = blockIdx.x * 4 + wave;

    float d0 = 0.f, d1 = 0.f;
#pragma unroll
    for (int half = 0; half < 2; ++half) {
        const int col = lane + half * 64;
        const float mu  = (float)(sums[col]  * (1.0 / 8192.0));
        const float ex2 = (float)(sumsq[col] * (1.0 / 8192.0));
        const float var = ex2 - mu * mu;
        const float inv = rsqrtf(var + 1e-5f);
        const float v = (o1[(size_t)row * 128 + col] - mu) * inv * gamma[col] + beta[col];
        d0 = fmaf(v, fc2w[col],       d0);
        d1 = fmaf(v, fc2w[128 + col], d1);
    }
#pragma unroll
    for (int off = 32; off >= 1; off >>= 1) {
        d0 += __shfl_down(d0, off);
        d1 += __shfl_down(d1, off);
    }
    if (lane == 0) {
        const float y0 = selu(d0 + fc2b[0]);
        const float y1 = selu(d1 + fc2b[1]);
        o_out[(size_t)row * 2 + 0] = y0;
        o_out[(size_t)row * 2 + 1] = y1;
        packed[row] = make_float4(y0, y1, y0 * y0 + y1 * y1, 0.f);
    }
}

// ---------------- Kernel D: denom = 2 * sum_{i<j} 1/(1+dis) -----------------
__global__ __launch_bounds__(256) void denom_reduce(
    const float4* __restrict__ packed, double* __restrict__ denom)
{
    const int rb = blockIdx.x * 64;
    const int cb = blockIdx.y * 1024;
    if (cb + 1024 <= rb) return;
    const int t = threadIdx.x;
    const bool full = (cb >= rb + 64);

    float4 cd[4];
#pragma unroll
    for (int u = 0; u < 4; ++u) cd[u] = packed[cb + t + u * 256];

    float accf = 0.f;
#pragma unroll 4
    for (int r = 0; r < 64; ++r) {
        const int i = rb + r;
        const float4 pi = packed[i];
#pragma unroll
        for (int u = 0; u < 4; ++u) {
            float dis = pi.z + cd[u].z - 2.f * fmaf(pi.x, cd[u].x, pi.y * cd[u].y);
            dis = fmaxf(dis, 0.f);
            float f = fast_rcp(1.f + dis);
            if (!full) {
                const int j = cb + t + u * 256;
                f = (j > i) ? f : 0.f;
            }
            accf += f;
        }
    }
#pragma unroll
    for (int off = 32; off >= 1; off >>= 1) accf += __shfl_down(accf, off);
    __shared__ double wsum[4];
    const int wave = t >> 6, lane = t & 63;
    if (lane == 0) wsum[wave] = (double)accf;
    __syncthreads();
    if (t == 0) atomicAdd(denom, 2.0 * (wsum[0] + wsum[1] + wsum[2] + wsum[3]));
}

// ---------------- Kernel E: qij write, slab layout (at write floor) ---------
__global__ __launch_bounds__(512) void qij_write_slab(
    const float4* __restrict__ packed, const double* __restrict__ denom,
    float* __restrict__ qij)
{
    const int t  = threadIdx.x;              // 0..511
    const int rb = blockIdx.x * 16;
    const float inv = (float)(1.0 / denom[0]);

    float4 cd[4][4];
#pragma unroll
    for (int c = 0; c < 4; ++c)
#pragma unroll
        for (int u = 0; u < 4; ++u)
            cd[c][u] = packed[c * 2048 + t * 4 + u];

#pragma unroll 2
    for (int r = 0; r < 16; ++r) {
        const int j = rb + r;
        const float4 pi = packed[j];
        float* outrow = qij + (size_t)j * 8192 + t * 4;
#pragma unroll
        for (int c = 0; c < 4; ++c) {
            floatx4 q;
#pragma unroll
            for (int u = 0; u < 4; ++u) {
                float dis = pi.z + cd[c][u].z
                          - 2.f * fmaf(pi.x, cd[c][u].x, pi.y * cd[c][u].y);
                dis = fmaxf(dis, 0.f);
                q[u] = inv * fast_rcp(1.f + dis);
            }
            *reinterpret_cast<floatx4*>(outrow + c * 2048) = q;
        }
    }
}

// ---------------------------------------------------------------------------
extern "C" void kernel_launch(void* const* d_in, const int* in_sizes, int n_in,
                              void* d_out, int out_size, void* d_ws, size_t ws_size,
                              hipStream_t stream)
{
    const float* x      = (const float*)d_in[0];
    const float* fc_w   = (const float*)d_in[1];
    const float* fc_b   = (const float*)d_in[2];
    const float* gamma  = (const float*)d_in[3];
    const float* beta   = (const float*)d_in[4];
    const float* fc2_w  = (const float*)d_in[5];
    const float* fc2_b  = (const float*)d_in[6];

    constexpr int N = 8192;

    float* qij   = (float*)d_out;                          // [N, N]
    float* o_out = (float*)d_out + (size_t)N * N;          // [N, 2]

    char* ws = (char*)d_ws;
    constexpr size_t O1_OFF     = 0;                          // 4 MB
    constexpr size_t ACC_OFF    = (size_t)N * 128 * 4;        // 257 doubles
    constexpr size_t SH_OFF     = ACC_OFF + 4096;             // 8192 doubles
    constexpr size_t PACKED_OFF = SH_OFF + 65536;             // 128 KB
    constexpr size_t WHI_OFF    = PACKED_OFF + (size_t)N * 16;
    constexpr size_t WPLANE     = ((size_t)128 * 832 * 2 + 63) / 64 * 64;
    constexpr size_t WLO_OFF    = WHI_OFF + WPLANE;

    float*  o1     = (float*)(ws + O1_OFF);
    double* accs   = (double*)(ws + ACC_OFF);              // sums|sumsq|denom
    double* sums   = accs;
    double* sumsq  = accs + 128;
    double* denom  = accs + 256;
    double* shards = (double*)(ws + SH_OFF);               // [2][32][128]
    float4* packed = (float4*)(ws + PACKED_OFF);
    ushort* whi    = (ushort*)(ws + WHI_OFF);
    ushort* wlo    = (ushort*)(ws + WLO_OFF);

    // W: convert fc_w to bf16 hi/lo planes (K padded to 832), zero shards
    convert_w_pad<<<128, 256, 0, stream>>>(fc_w, whi, wlo, shards, accs);

    // A: BK-tiled LDS MFMA GEMM + sharded stats
    gemm1_tiled_stats<<<dim3(N / 64, 2), 256, 0, stream>>>(x, whi, wlo, fc_b, o1, shards);

    // R: fold shards -> sums / sumsq
    reduce_stats<<<1, 256, 0, stream>>>(shards, accs);

    // C: normalize + fc2 + selu -> o_out, packed
    bn_fc2_selu<<<N / 4, 256, 0, stream>>>(o1, sums, sumsq, gamma, beta, fc2_w, fc2_b, o_out, packed);

    // D: denom = 2 * sum_{i<j} 1/(1+dis)
    denom_reduce<<<dim3(N / 64, N / 1024), 256, 0, stream>>>(packed, denom);

    // E: qij = (1/denom) / (1 + dis)
    qij_write_slab<<<512, 512, 0, stream>>>(packed, denom, qij);
}